// Round 19
// baseline (130.098 us; speedup 1.0000x reference)
//
#include <hip/hip_runtime.h>

#define N_NODES 50000
#define N_EDGES 800000
#define F 128
#define ROWB 384   // uxt row: [0,128)=u fp8, [128,384)=xt bf16
#define NPART 8    // histogram partitions (contention / line-sharing reduction)

typedef unsigned short u16;
typedef __bf16 bf16x8 __attribute__((ext_vector_type(8)));
typedef float f32x4 __attribute__((ext_vector_type(4)));
typedef float f32x2 __attribute__((ext_vector_type(2)));

__device__ inline u16 f2bf(float f) {
  union { float f; unsigned u; } v; v.f = f;
  unsigned r = v.u + 0x7fffu + ((v.u >> 16) & 1u);
  return (u16)(r >> 16);
}

__device__ inline int clampi(int v) {
  v = v < 0 ? 0 : v;
  return v >= N_NODES ? N_NODES - 1 : v;
}

// fp8 e4m3 cvt via HW instruction (builtin if present, else inline asm)
__device__ inline f32x2 fp8x2_to_f32(unsigned w) {
#if __has_builtin(__builtin_amdgcn_cvt_pk_f32_fp8)
  return __builtin_amdgcn_cvt_pk_f32_fp8((int)w, false);
#else
  f32x2 r;
  asm("v_cvt_pk_f32_fp8 %0, %1" : "=v"(r) : "v"(w));
  return r;
#endif
}
__device__ inline unsigned f32_to_fp8(float a) {
#if __has_builtin(__builtin_amdgcn_cvt_pk_fp8_f32)
  return (unsigned)__builtin_amdgcn_cvt_pk_fp8_f32(a, a, 0, false) & 0xffu;
#else
  unsigned r;
  asm("v_cvt_pk_fp8_f32 %0, %1, %2" : "=v"(r) : "v"(a), "v"(a));
  return r & 0xffu;
#endif
}

// fast reciprocal (1 instruction; ~1ulp — fine for a sigmoid gate)
__device__ inline float fast_rcp(float a) {
  float r;
  asm("v_rcp_f32 %0, %1" : "=v"(r) : "v"(a));
  return r;
}

// load 8 contiguous fp32 -> bf16x8 fragment
__device__ inline bf16x8 pack8(const float* __restrict__ p) {
  float4 a = *(const float4*)p;
  float4 b = *(const float4*)(p + 4);
  bf16x8 r;
  r[0] = (__bf16)a.x; r[1] = (__bf16)a.y; r[2] = (__bf16)a.z; r[3] = (__bf16)a.w;
  r[4] = (__bf16)b.x; r[5] = (__bf16)b.y; r[6] = (__bf16)b.z; r[7] = (__bf16)b.w;
  return r;
}

// ---------- pre: zero partitioned deg | transpose weights ----------
#define ZERO_BLOCKS 1563  // ceil(8*50000/256)
#define PREP_BLOCKS 192
__global__ __launch_bounds__(256) void pre_kernel(
    int* __restrict__ degp,
    const float* __restrict__ W, const float* __restrict__ W1,
    u16* __restrict__ wt, u16* __restrict__ w1t2)
{
  int bid = blockIdx.x;
  if (bid < ZERO_BLOCKS) {
    int i = bid * 256 + threadIdx.x;
    if (i < NPART * N_NODES) degp[i] = 0;
  } else {
    int t = (bid - ZERO_BLOCKS) * 256 + threadIdx.x;  // 0 .. 49151
    if (t < 128 * 128) {
      int k = t >> 7, n = t & 127;
      wt[n * 128 + k] = f2bf(W[k * 128 + n]);
    } else {
      int t2 = t - 128 * 128;           // 0 .. 32767
      int n2 = t2 >> 7, k = t2 & 127;   // n2: 0..255
      float v = (n2 < 128) ? W1[k * 128 + n2] : W1[(128 + k) * 128 + (n2 - 128)];
      w1t2[n2 * 128 + k] = f2bf(v);
    }
  }
}

// ---------- partitioned histogram: partition = blockIdx & 7 ----------
#define HIST_BLOCKS 3125   // 800000 / 256 exactly
__global__ __launch_bounds__(256) void hist_kernel(
    const int* __restrict__ ei, int* __restrict__ degp, int* __restrict__ loc)
{
  int e = blockIdx.x * 256 + threadIdx.x;
  int p = blockIdx.x & (NPART - 1);
  int d = clampi(ei[N_EDGES + e]);
  loc[e] = atomicAdd(&degp[p * N_NODES + d], 1);
}

// ---------- scan1: per-node total + partition partials + block-local scan ----------
#define SCAN_BLOCKS 49
__global__ __launch_bounds__(1024) void scan1_kernel(const int* __restrict__ degp,
                                                     int* __restrict__ offsets,
                                                     int4* __restrict__ pb4a,
                                                     int4* __restrict__ pb4b,
                                                     int* __restrict__ bsum) {
  __shared__ int wsum[16];
  int t = threadIdx.x, lane = t & 63, wid = t >> 6;
  int i = blockIdx.x * 1024 + t;
  int d[NPART];
#pragma unroll
  for (int pp = 0; pp < NPART; pp++)
    d[pp] = (i < N_NODES) ? degp[pp * N_NODES + i] : 0;
  int pb[NPART];
  pb[0] = 0;
#pragma unroll
  for (int pp = 1; pp < NPART; pp++) pb[pp] = pb[pp - 1] + d[pp - 1];
  int v = pb[NPART - 1] + d[NPART - 1];
  int s = v;
#pragma unroll
  for (int dd = 1; dd < 64; dd <<= 1) {
    int u = __shfl_up(s, dd);
    if (lane >= dd) s += u;
  }
  if (lane == 63) wsum[wid] = s;
  __syncthreads();
  if (wid == 0 && lane < 16) {
    int ws = wsum[lane];
#pragma unroll
    for (int dd = 1; dd < 16; dd <<= 1) {
      int u = __shfl_up(ws, dd);
      if (lane >= dd) ws += u;
    }
    wsum[lane] = ws;
  }
  __syncthreads();
  int wprev = (wid == 0) ? 0 : wsum[wid - 1];
  if (i < N_NODES) {
    offsets[i] = wprev + s - v;  // block-local exclusive
    int4 a; a.x = pb[0]; a.y = pb[1]; a.z = pb[2]; a.w = pb[3];
    int4 b; b.x = pb[4]; b.y = pb[5]; b.z = pb[6]; b.w = pb[7];
    pb4a[i] = a; pb4b[i] = b;
  }
  if (t == 0) bsum[blockIdx.x] = wsum[15];
}

// ---------- scan23: add block base; emit per-partition obase ----------
__global__ __launch_bounds__(256) void scan23_kernel(int* __restrict__ offsets,
                                                     const int* __restrict__ bsum,
                                                     const int4* __restrict__ pb4a,
                                                     const int4* __restrict__ pb4b,
                                                     int* __restrict__ obase) {
  __shared__ int base[SCAN_BLOCKS + 1];
  if (threadIdx.x < 64) {
    int t = threadIdx.x;
    int v = (t < SCAN_BLOCKS) ? bsum[t] : 0;
    int s = v;
#pragma unroll
    for (int dd = 1; dd < 64; dd <<= 1) {
      int u = __shfl_up(s, dd);
      if (t >= dd) s += u;
    }
    if (t < SCAN_BLOCKS) base[t] = s - v;
    if (t == SCAN_BLOCKS - 1) base[SCAN_BLOCKS] = s;
  }
  __syncthreads();
  int i = blockIdx.x * blockDim.x + threadIdx.x;
  if (i < N_NODES) {
    int off = offsets[i] + base[i >> 10];
    offsets[i] = off;
    int4 a = pb4a[i];
    int4 b = pb4b[i];
    obase[0 * N_NODES + i] = off + a.x;
    obase[1 * N_NODES + i] = off + a.y;
    obase[2 * N_NODES + i] = off + a.z;
    obase[3 * N_NODES + i] = off + a.w;
    obase[4 * N_NODES + i] = off + b.x;
    obase[5 * N_NODES + i] = off + b.y;
    obase[6 * N_NODES + i] = off + b.z;
    obase[7 * N_NODES + i] = off + b.w;
  }
  if (i == 0) offsets[N_NODES] = base[SCAN_BLOCKS];
}

// ---------- reorder: atomic-free scatter via partitioned base ----------
__global__ void reorder_kernel(const int* __restrict__ ei, const int* __restrict__ obase,
                               const int* __restrict__ loc, u16* __restrict__ srcs16) {
  int e = blockIdx.x * blockDim.x + threadIdx.x;
  if (e < N_EDGES) {
    int p = (e >> 8) & (NPART - 1);
    int s = clampi(ei[e]);
    int d = clampi(ei[N_EDGES + e]);
    srcs16[obase[p * N_NODES + d] + loc[e]] = (u16)s;
  }
}

// ---------- node GEMMs (standalone, r13-proven): xt(bf16), u(fp8), v(bf16) ----------
__global__ __launch_bounds__(256) void node_gemm_kernel(
    const float* __restrict__ x, const u16* __restrict__ wt,
    const u16* __restrict__ w1t2, const float* __restrict__ bias,
    const float* __restrict__ b1,
    unsigned char* __restrict__ uxt, u16* __restrict__ vout)
{
  __shared__ u16 wl[128 * 128];  // 32KB, slot XOR-swizzled by (row&7)
  int w = threadIdx.x >> 6, l = threadIdx.x & 63;
  int r2 = l & 15, q = l >> 4;
  int sw = r2 & 7;
  int rowbase = blockIdx.x * 64 + w * 16;
  int ra = rowbase + r2;  if (ra >= N_NODES) ra = N_NODES - 1;
  bf16x8 A[4];
#pragma unroll
  for (int k = 0; k < 4; k++)
    A[k] = pack8(x + ra * F + q * 8 + 32 * k);

  // ---- phase 1: stage wt; xt = x@W + b -> uxt[.][128:384) bf16 ----
  for (int c = threadIdx.x; c < 128 * 16; c += 256) {
    int row = c >> 4, slot = c & 15;
    *(bf16x8*)&wl[row * 128 + ((slot ^ (row & 7)) << 3)] =
        *(const bf16x8*)(wt + row * 128 + slot * 8);
  }
  __syncthreads();
  {
    float bv[8];
#pragma unroll
    for (int nf = 0; nf < 8; nf++) bv[nf] = bias[r2 + 16 * nf];
    f32x4 acc[8] = {};
#pragma unroll
    for (int k = 0; k < 4; k++) {
#pragma unroll
      for (int nf = 0; nf < 8; nf++) {
        bf16x8 b = *(const bf16x8*)&wl[(16 * nf + r2) * 128 + (((q + 4 * k) ^ sw) << 3)];
        acc[nf] = __builtin_amdgcn_mfma_f32_16x16x32_bf16(A[k], b, acc[nf], 0, 0, 0);
      }
    }
#pragma unroll
    for (int nf = 0; nf < 8; nf++) {
#pragma unroll
      for (int r = 0; r < 4; r++) {
        int row = rowbase + 4 * q + r;
        int c = r2 + 16 * nf;
        if (row < N_NODES)
          *(u16*)(uxt + (size_t)row * ROWB + 128 + 2 * c) = f2bf(acc[nf][r] + bv[nf]);
      }
    }
  }
  __syncthreads();
  // ---- phase 2: stage W1s; u = x@W1s -> uxt[.][0:128) fp8 ----
  for (int c = threadIdx.x; c < 128 * 16; c += 256) {
    int row = c >> 4, slot = c & 15;
    *(bf16x8*)&wl[row * 128 + ((slot ^ (row & 7)) << 3)] =
        *(const bf16x8*)(w1t2 + row * 128 + slot * 8);
  }
  __syncthreads();
  {
    f32x4 acc[8] = {};
#pragma unroll
    for (int k = 0; k < 4; k++) {
#pragma unroll
      for (int nf = 0; nf < 8; nf++) {
        bf16x8 b = *(const bf16x8*)&wl[(16 * nf + r2) * 128 + (((q + 4 * k) ^ sw) << 3)];
        acc[nf] = __builtin_amdgcn_mfma_f32_16x16x32_bf16(A[k], b, acc[nf], 0, 0, 0);
      }
    }
#pragma unroll
    for (int nf = 0; nf < 8; nf++) {
#pragma unroll
      for (int r = 0; r < 4; r++) {
        int row = rowbase + 4 * q + r;
        int c = r2 + 16 * nf;
        if (row < N_NODES)
          uxt[(size_t)row * ROWB + c] = (unsigned char)f32_to_fp8(acc[nf][r]);
      }
    }
  }
  __syncthreads();
  // ---- phase 3: stage W1d; v = x@W1d + b1 -> vout bf16 ----
  for (int c = threadIdx.x; c < 128 * 16; c += 256) {
    int row = c >> 4, slot = c & 15;
    *(bf16x8*)&wl[row * 128 + ((slot ^ (row & 7)) << 3)] =
        *(const bf16x8*)(w1t2 + 128 * 128 + row * 128 + slot * 8);
  }
  __syncthreads();
  {
    float b1v[8];
#pragma unroll
    for (int nf = 0; nf < 8; nf++) b1v[nf] = b1[r2 + 16 * nf];
    f32x4 acc[8] = {};
#pragma unroll
    for (int k = 0; k < 4; k++) {
#pragma unroll
      for (int nf = 0; nf < 8; nf++) {
        bf16x8 b = *(const bf16x8*)&wl[(16 * nf + r2) * 128 + (((q + 4 * k) ^ sw) << 3)];
        acc[nf] = __builtin_amdgcn_mfma_f32_16x16x32_bf16(A[k], b, acc[nf], 0, 0, 0);
      }
    }
#pragma unroll
    for (int nf = 0; nf < 8; nf++) {
#pragma unroll
      for (int r = 0; r < 4; r++) {
        int row = rowbase + 4 * q + r;
        int c = r2 + 16 * nf;
        if (row < N_NODES) vout[row * F + c] = f2bf(acc[nf][r] + b1v[nf]);
      }
    }
  }
}

// ---------- fused gate + aggregate: one wave per dst node, 8 slots/iter ----------
__global__ __launch_bounds__(256) void edge_fused_kernel(
    const unsigned char* __restrict__ uxt, const u16* __restrict__ v,
    const int* __restrict__ offsets, const u16* __restrict__ srcs16,
    const float* __restrict__ w2f, const float* __restrict__ b2,
    float* __restrict__ out)
{
  int n = (blockIdx.x * blockDim.x + threadIdx.x) >> 6;
  if (n >= N_NODES) return;
  int lane = threadIdx.x & 63;
  int g = lane >> 4, j = lane & 15;
  float w2v[8], vn[8];
  float4 wa = *(const float4*)(w2f + 8 * j);
  float4 wb = *(const float4*)(w2f + 8 * j + 4);
  w2v[0] = wa.x; w2v[1] = wa.y; w2v[2] = wa.z; w2v[3] = wa.w;
  w2v[4] = wb.x; w2v[5] = wb.y; w2v[6] = wb.z; w2v[7] = wb.w;
  bf16x8 vv = *(const bf16x8*)(v + n * F + 8 * j);
#pragma unroll
  for (int i = 0; i < 8; i++) vn[i] = (float)vv[i];
  float bias2 = b2[0];
  float acc[8] = {};
  int p = offsets[n], end = offsets[n + 1];
  const unsigned char* uA = uxt + 8 * j;           // u chunk base (per-lane)
  const unsigned char* uB = uxt + 128 + 16 * j;    // xt chunk base (per-lane)
  for (int base = p; base < end; base += 8) {
    int s0 = base + g, s1 = base + 4 + g;
    bool vld0 = s0 < end, vld1 = s1 < end;
    int sp0 = srcs16[vld0 ? s0 : end - 1];
    int sp1 = srcs16[vld1 ? s1 : end - 1];
    int o0 = sp0 * ROWB;
    int o1 = sp1 * ROWB;
    uint2 up0 = *(const uint2*)(uA + o0);
    bf16x8 xx0 = *(const bf16x8*)(uB + o0);
    uint2 up1 = *(const uint2*)(uA + o1);
    bf16x8 xx1 = *(const bf16x8*)(uB + o1);
    f32x2 a0 = fp8x2_to_f32(up0.x & 0xffffu), a1 = fp8x2_to_f32(up0.x >> 16);
    f32x2 a2 = fp8x2_to_f32(up0.y & 0xffffu), a3 = fp8x2_to_f32(up0.y >> 16);
    f32x2 b0 = fp8x2_to_f32(up1.x & 0xffffu), b1x = fp8x2_to_f32(up1.x >> 16);
    f32x2 b2x = fp8x2_to_f32(up1.y & 0xffffu), b3 = fp8x2_to_f32(up1.y >> 16);
    float u0[8] = {a0[0], a0[1], a1[0], a1[1], a2[0], a2[1], a3[0], a3[1]};
    float u1[8] = {b0[0], b0[1], b1x[0], b1x[1], b2x[0], b2x[1], b3[0], b3[1]};
    float t0 = 0.f, t1 = 0.f;
#pragma unroll
    for (int i = 0; i < 8; i++) {
      float h0 = u0[i] + vn[i]; h0 = h0 > 0.f ? h0 : 0.f;
      float h1 = u1[i] + vn[i]; h1 = h1 > 0.f ? h1 : 0.f;
      t0 += h0 * w2v[i];
      t1 += h1 * w2v[i];
    }
#pragma unroll
    for (int d = 1; d < 16; d <<= 1) {
      t0 += __shfl_xor(t0, d);
      t1 += __shfl_xor(t1, d);
    }
    float g0 = fast_rcp(1.0f + __expf(-(t0 + bias2)));
    float g1 = fast_rcp(1.0f + __expf(-(t1 + bias2)));
    g0 = vld0 ? g0 : 0.f;
    g1 = vld1 ? g1 : 0.f;
#pragma unroll
    for (int i = 0; i < 8; i++) {
      acc[i] += g0 * (float)xx0[i];
      acc[i] += g1 * (float)xx1[i];
    }
  }
#pragma unroll
  for (int i = 0; i < 8; i++) acc[i] += __shfl_xor(acc[i], 16);
#pragma unroll
  for (int i = 0; i < 8; i++) acc[i] += __shfl_xor(acc[i], 32);
  if (g == 0) {
    float4 o0, o1;
    o0.x = acc[0]; o0.y = acc[1]; o0.z = acc[2]; o0.w = acc[3];
    o1.x = acc[4]; o1.y = acc[5]; o1.z = acc[6]; o1.w = acc[7];
    *(float4*)(out + n * F + 8 * j) = o0;
    *(float4*)(out + n * F + 8 * j + 4) = o1;
  }
}

extern "C" void kernel_launch(void* const* d_in, const int* in_sizes, int n_in,
                              void* d_out, int out_size, void* d_ws, size_t ws_size,
                              hipStream_t stream) {
  const float* x  = (const float*)d_in[0];
  const int* ei   = (const int*)d_in[1];   // int64 in reference -> int32 in harness
  const float* W  = (const float*)d_in[2];
  const float* b  = (const float*)d_in[3];
  const float* W1 = (const float*)d_in[4];
  const float* b1 = (const float*)d_in[5];
  const float* W2 = (const float*)d_in[6];
  const float* b2 = (const float*)d_in[7];
  float* out = (float*)d_out;

  char* ws = (char*)d_ws;
  unsigned char* uxt = (unsigned char*)ws;    // 19,200,000 B  [n]: u fp8 | xt bf16
  u16* vout    = (u16*)(ws + 19200000);       // 12,800,000 B
  u16* wt      = (u16*)(ws + 32000000);       //     32,768 B
  u16* w1t2    = (u16*)(ws + 32032768);       //     65,536 B
  int* offsets = (int*)(ws + 32098304);       //    200,004 B
  int* degp    = (int*)(ws + 32298308);       //  1,600,000 B  (8 partitions)
  int4* pb4a   = (int4*)(ws + 33898308);      //    800,000 B
  int4* pb4b   = (int4*)(ws + 34698308);      //    800,000 B
  int* obase   = (int*)(ws + 35498308);       //  1,600,000 B
  int* loc     = (int*)(ws + 37098308);       //  3,200,000 B
  u16* srcs16  = (u16*)(ws + 40298308);       //  1,600,000 B
  int* bsum    = (int*)(ws + 41898308);       //        196 B   total ~41.9 MB
  (void)ws_size;

  pre_kernel<<<ZERO_BLOCKS + PREP_BLOCKS, 256, 0, stream>>>(degp, W, W1, wt, w1t2);
  hist_kernel<<<HIST_BLOCKS, 256, 0, stream>>>(ei, degp, loc);
  scan1_kernel<<<SCAN_BLOCKS, 1024, 0, stream>>>(degp, offsets, pb4a, pb4b, bsum);
  scan23_kernel<<<(N_NODES + 255) / 256, 256, 0, stream>>>(offsets, bsum, pb4a, pb4b, obase);
  reorder_kernel<<<(N_EDGES + 255) / 256, 256, 0, stream>>>(ei, obase, loc, srcs16);
  node_gemm_kernel<<<(N_NODES + 63) / 64, 256, 0, stream>>>(x, wt, w1t2, b, b1, uxt, vout);
  edge_fused_kernel<<<(N_NODES * 64 + 255) / 256, 256, 0, stream>>>(
      uxt, vout, offsets, srcs16, W2, b2, out);
}

// Round 20
// 127.357 us; speedup vs baseline: 1.0215x; 1.0215x over previous
//
#include <hip/hip_runtime.h>

#define N_NODES 50000
#define N_EDGES 800000
#define F 128
#define ROWB 384   // uxt row: [0,128)=u fp8, [128,384)=xt bf16
#define NPART 4    // histogram partitions

typedef unsigned short u16;
typedef __bf16 bf16x8 __attribute__((ext_vector_type(8)));
typedef float f32x4 __attribute__((ext_vector_type(4)));
typedef float f32x2 __attribute__((ext_vector_type(2)));

__device__ inline u16 f2bf(float f) {
  union { float f; unsigned u; } v; v.f = f;
  unsigned r = v.u + 0x7fffu + ((v.u >> 16) & 1u);
  return (u16)(r >> 16);
}

__device__ inline int clampi(int v) {
  v = v < 0 ? 0 : v;
  return v >= N_NODES ? N_NODES - 1 : v;
}

// fp8 e4m3 cvt via HW instruction (builtin if present, else inline asm)
__device__ inline f32x2 fp8x2_to_f32(unsigned w) {
#if __has_builtin(__builtin_amdgcn_cvt_pk_f32_fp8)
  return __builtin_amdgcn_cvt_pk_f32_fp8((int)w, false);
#else
  f32x2 r;
  asm("v_cvt_pk_f32_fp8 %0, %1" : "=v"(r) : "v"(w));
  return r;
#endif
}
__device__ inline unsigned f32_to_fp8(float a) {
#if __has_builtin(__builtin_amdgcn_cvt_pk_fp8_f32)
  return (unsigned)__builtin_amdgcn_cvt_pk_fp8_f32(a, a, 0, false) & 0xffu;
#else
  unsigned r;
  asm("v_cvt_pk_fp8_f32 %0, %1, %2" : "=v"(r) : "v"(a), "v"(a));
  return r & 0xffu;
#endif
}

// load 8 contiguous fp32 -> bf16x8 fragment
__device__ inline bf16x8 pack8(const float* __restrict__ p) {
  float4 a = *(const float4*)p;
  float4 b = *(const float4*)(p + 4);
  bf16x8 r;
  r[0] = (__bf16)a.x; r[1] = (__bf16)a.y; r[2] = (__bf16)a.z; r[3] = (__bf16)a.w;
  r[4] = (__bf16)b.x; r[5] = (__bf16)b.y; r[6] = (__bf16)b.z; r[7] = (__bf16)b.w;
  return r;
}

// ---------- pre: zero partitioned deg | transpose weights ----------
#define ZERO_BLOCKS 782   // ceil(4*50000/256)
#define PREP_BLOCKS 192
__global__ __launch_bounds__(256) void pre_kernel(
    int* __restrict__ degp,
    const float* __restrict__ W, const float* __restrict__ W1,
    u16* __restrict__ wt, u16* __restrict__ w1t2)
{
  int bid = blockIdx.x;
  if (bid < ZERO_BLOCKS) {
    int i = bid * 256 + threadIdx.x;
    if (i < NPART * N_NODES) degp[i] = 0;
  } else {
    int t = (bid - ZERO_BLOCKS) * 256 + threadIdx.x;  // 0 .. 49151
    if (t < 128 * 128) {
      int k = t >> 7, n = t & 127;
      wt[n * 128 + k] = f2bf(W[k * 128 + n]);
    } else {
      int t2 = t - 128 * 128;           // 0 .. 32767
      int n2 = t2 >> 7, k = t2 & 127;   // n2: 0..255
      float v = (n2 < 128) ? W1[k * 128 + n2] : W1[(128 + k) * 128 + (n2 - 128)];
      w1t2[n2 * 128 + k] = f2bf(v);
    }
  }
}

// ---------- partitioned histogram: partition = blockIdx & 3 ----------
#define HIST_BLOCKS 3125   // 800000 / 256 exactly
__global__ __launch_bounds__(256) void hist_kernel(
    const int* __restrict__ ei, int* __restrict__ degp, int* __restrict__ loc)
{
  int e = blockIdx.x * 256 + threadIdx.x;
  int p = blockIdx.x & (NPART - 1);
  int d = clampi(ei[N_EDGES + e]);
  loc[e] = atomicAdd(&degp[p * N_NODES + d], 1);
}

// ---------- scan1: per-node total + partition partials + block-local scan ----------
#define SCAN_BLOCKS 49
__global__ __launch_bounds__(1024) void scan1_kernel(const int* __restrict__ degp,
                                                     int* __restrict__ offsets,
                                                     int4* __restrict__ pb4,
                                                     int* __restrict__ bsum) {
  __shared__ int wsum[16];
  int t = threadIdx.x, lane = t & 63, wid = t >> 6;
  int i = blockIdx.x * 1024 + t;
  int d0 = 0, d1 = 0, d2 = 0, d3 = 0;
  if (i < N_NODES) {
    d0 = degp[i];
    d1 = degp[N_NODES + i];
    d2 = degp[2 * N_NODES + i];
    d3 = degp[3 * N_NODES + i];
  }
  int v = d0 + d1 + d2 + d3;
  int s = v;
#pragma unroll
  for (int d = 1; d < 64; d <<= 1) {
    int u = __shfl_up(s, d);
    if (lane >= d) s += u;
  }
  if (lane == 63) wsum[wid] = s;
  __syncthreads();
  if (wid == 0 && lane < 16) {
    int ws = wsum[lane];
#pragma unroll
    for (int d = 1; d < 16; d <<= 1) {
      int u = __shfl_up(ws, d);
      if (lane >= d) ws += u;
    }
    wsum[lane] = ws;
  }
  __syncthreads();
  int wprev = (wid == 0) ? 0 : wsum[wid - 1];
  if (i < N_NODES) {
    offsets[i] = wprev + s - v;  // block-local exclusive
    int4 pb; pb.x = 0; pb.y = d0; pb.z = d0 + d1; pb.w = d0 + d1 + d2;
    pb4[i] = pb;
  }
  if (t == 0) bsum[blockIdx.x] = wsum[15];
}

// ---------- scan23: add block base; emit per-partition obase ----------
__global__ __launch_bounds__(256) void scan23_kernel(int* __restrict__ offsets,
                                                     const int* __restrict__ bsum,
                                                     const int4* __restrict__ pb4,
                                                     int* __restrict__ obase) {
  __shared__ int base[SCAN_BLOCKS + 1];
  if (threadIdx.x < 64) {
    int t = threadIdx.x;
    int v = (t < SCAN_BLOCKS) ? bsum[t] : 0;
    int s = v;
#pragma unroll
    for (int d = 1; d < 64; d <<= 1) {
      int u = __shfl_up(s, d);
      if (t >= d) s += u;
    }
    if (t < SCAN_BLOCKS) base[t] = s - v;
    if (t == SCAN_BLOCKS - 1) base[SCAN_BLOCKS] = s;
  }
  __syncthreads();
  int i = blockIdx.x * blockDim.x + threadIdx.x;
  if (i < N_NODES) {
    int off = offsets[i] + base[i >> 10];
    offsets[i] = off;
    int4 pb = pb4[i];
    obase[0 * N_NODES + i] = off + pb.x;
    obase[1 * N_NODES + i] = off + pb.y;
    obase[2 * N_NODES + i] = off + pb.z;
    obase[3 * N_NODES + i] = off + pb.w;
  }
  if (i == 0) offsets[N_NODES] = base[SCAN_BLOCKS];
}

// ---------- reorder: atomic-free scatter via partitioned base ----------
__global__ void reorder_kernel(const int* __restrict__ ei, const int* __restrict__ obase,
                               const int* __restrict__ loc, u16* __restrict__ srcs16) {
  int e = blockIdx.x * blockDim.x + threadIdx.x;
  if (e < N_EDGES) {
    int p = (e >> 8) & (NPART - 1);
    int s = clampi(ei[e]);
    int d = clampi(ei[N_EDGES + e]);
    srcs16[obase[p * N_NODES + d] + loc[e]] = (u16)s;
  }
}

// ---------- node GEMMs: xt(bf16), u(fp8), v(bf16); wide stores via wl reuse ----------
// After each phase's MFMAs, fragments are transposed through the (now idle) wl
// LDS buffer per-wave (wave-private slice -> no extra barrier), then stored as
// contiguous 128-256B row segments (fully-dirty 64B lines). r16 diagnosis:
// per-lane 1-2B scattered fragment stores caused partial-line writeback bloat.
__global__ __launch_bounds__(256) void node_gemm_kernel(
    const float* __restrict__ x, const u16* __restrict__ wt,
    const u16* __restrict__ w1t2, const float* __restrict__ bias,
    const float* __restrict__ b1,
    unsigned char* __restrict__ uxt, u16* __restrict__ vout)
{
  __shared__ u16 wl[128 * 128];  // 32KB: weights (swizzled) OR per-wave transpose buf
  int w = threadIdx.x >> 6, l = threadIdx.x & 63;
  int r2 = l & 15, q = l >> 4;
  int sw = r2 & 7;
  int rowbase = blockIdx.x * 64 + w * 16;
  int ra = rowbase + r2;  if (ra >= N_NODES) ra = N_NODES - 1;
  // per-wave transpose slice: 16 rows x 272B (=136 u16), 4.25KB/wave
  u16* tw = wl + w * 16 * 136;
  unsigned char* tb = (unsigned char*)tw;
  bf16x8 A[4];
#pragma unroll
  for (int k = 0; k < 4; k++)
    A[k] = pack8(x + ra * F + q * 8 + 32 * k);

  // ---- phase 1: stage wt; xt = x@W + b -> uxt[.][128:384) bf16 ----
  for (int c = threadIdx.x; c < 128 * 16; c += 256) {
    int row = c >> 4, slot = c & 15;
    *(bf16x8*)&wl[row * 128 + ((slot ^ (row & 7)) << 3)] =
        *(const bf16x8*)(wt + row * 128 + slot * 8);
  }
  __syncthreads();
  {
    float bv[8];
#pragma unroll
    for (int nf = 0; nf < 8; nf++) bv[nf] = bias[r2 + 16 * nf];
    f32x4 acc[8] = {};
#pragma unroll
    for (int k = 0; k < 4; k++) {
#pragma unroll
      for (int nf = 0; nf < 8; nf++) {
        bf16x8 b = *(const bf16x8*)&wl[(16 * nf + r2) * 128 + (((q + 4 * k) ^ sw) << 3)];
        acc[nf] = __builtin_amdgcn_mfma_f32_16x16x32_bf16(A[k], b, acc[nf], 0, 0, 0);
      }
    }
    __syncthreads();  // all waves done reading wl weights
#pragma unroll
    for (int nf = 0; nf < 8; nf++)
#pragma unroll
      for (int r = 0; r < 4; r++)
        tw[(4 * q + r) * 136 + 16 * nf + r2] = f2bf(acc[nf][r] + bv[nf]);
    // wave-private buffer: no barrier needed before readout
#pragma unroll
    for (int p = 0; p < 4; p++) {
      int rl = p * 4 + q;
      int grow = rowbase + rl;
      if (grow < N_NODES) {
        bf16x8 vd = *(const bf16x8*)(tw + rl * 136 + r2 * 8);
        *(bf16x8*)((u16*)(uxt + (size_t)grow * ROWB + 128) + r2 * 8) = vd;
      }
    }
  }
  __syncthreads();
  // ---- phase 2: stage W1s; u = x@W1s -> uxt[.][0:128) fp8 ----
  for (int c = threadIdx.x; c < 128 * 16; c += 256) {
    int row = c >> 4, slot = c & 15;
    *(bf16x8*)&wl[row * 128 + ((slot ^ (row & 7)) << 3)] =
        *(const bf16x8*)(w1t2 + row * 128 + slot * 8);
  }
  __syncthreads();
  {
    f32x4 acc[8] = {};
#pragma unroll
    for (int k = 0; k < 4; k++) {
#pragma unroll
      for (int nf = 0; nf < 8; nf++) {
        bf16x8 b = *(const bf16x8*)&wl[(16 * nf + r2) * 128 + (((q + 4 * k) ^ sw) << 3)];
        acc[nf] = __builtin_amdgcn_mfma_f32_16x16x32_bf16(A[k], b, acc[nf], 0, 0, 0);
      }
    }
    __syncthreads();
#pragma unroll
    for (int nf = 0; nf < 8; nf++)
#pragma unroll
      for (int r = 0; r < 4; r++)
        tb[(4 * q + r) * 272 + 16 * nf + r2] = (unsigned char)f32_to_fp8(acc[nf][r]);
#pragma unroll
    for (int p = 0; p < 2; p++) {
      int rl = p * 8 + (l >> 3);
      int grow = rowbase + rl;
      if (grow < N_NODES) {
        uint4 vd = *(const uint4*)(tb + rl * 272 + (l & 7) * 16);
        *(uint4*)(uxt + (size_t)grow * ROWB + (l & 7) * 16) = vd;
      }
    }
  }
  __syncthreads();
  // ---- phase 3: stage W1d; v = x@W1d + b1 -> vout bf16 ----
  for (int c = threadIdx.x; c < 128 * 16; c += 256) {
    int row = c >> 4, slot = c & 15;
    *(bf16x8*)&wl[row * 128 + ((slot ^ (row & 7)) << 3)] =
        *(const bf16x8*)(w1t2 + 128 * 128 + row * 128 + slot * 8);
  }
  __syncthreads();
  {
    float b1v[8];
#pragma unroll
    for (int nf = 0; nf < 8; nf++) b1v[nf] = b1[r2 + 16 * nf];
    f32x4 acc[8] = {};
#pragma unroll
    for (int k = 0; k < 4; k++) {
#pragma unroll
      for (int nf = 0; nf < 8; nf++) {
        bf16x8 b = *(const bf16x8*)&wl[(16 * nf + r2) * 128 + (((q + 4 * k) ^ sw) << 3)];
        acc[nf] = __builtin_amdgcn_mfma_f32_16x16x32_bf16(A[k], b, acc[nf], 0, 0, 0);
      }
    }
    __syncthreads();
#pragma unroll
    for (int nf = 0; nf < 8; nf++)
#pragma unroll
      for (int r = 0; r < 4; r++)
        tw[(4 * q + r) * 136 + 16 * nf + r2] = f2bf(acc[nf][r] + b1v[nf]);
#pragma unroll
    for (int p = 0; p < 4; p++) {
      int rl = p * 4 + q;
      int grow = rowbase + rl;
      if (grow < N_NODES) {
        bf16x8 vd = *(const bf16x8*)(tw + rl * 136 + r2 * 8);
        *(bf16x8*)(vout + grow * F + r2 * 8) = vd;
      }
    }
  }
}

// ---------- fused gate + aggregate: one wave per dst node (r18-proven) ----------
__global__ __launch_bounds__(256) void edge_fused_kernel(
    const unsigned char* __restrict__ uxt, const u16* __restrict__ v,
    const int* __restrict__ offsets, const u16* __restrict__ srcs16,
    const float* __restrict__ w2f, const float* __restrict__ b2,
    float* __restrict__ out)
{
  int n = (blockIdx.x * blockDim.x + threadIdx.x) >> 6;
  if (n >= N_NODES) return;
  int lane = threadIdx.x & 63;
  int g = lane >> 4, j = lane & 15;
  float w2v[8], vn[8];
  float4 wa = *(const float4*)(w2f + 8 * j);
  float4 wb = *(const float4*)(w2f + 8 * j + 4);
  w2v[0] = wa.x; w2v[1] = wa.y; w2v[2] = wa.z; w2v[3] = wa.w;
  w2v[4] = wb.x; w2v[5] = wb.y; w2v[6] = wb.z; w2v[7] = wb.w;
  bf16x8 vv = *(const bf16x8*)(v + n * F + 8 * j);
#pragma unroll
  for (int i = 0; i < 8; i++) vn[i] = (float)vv[i];
  float bias2 = b2[0];
  float acc[8] = {};
  int p = offsets[n], end = offsets[n + 1];
  for (int base = p; base < end; base += 4) {
    int slot = base + g;
    bool valid = slot < end;
    int sp = srcs16[valid ? slot : end - 1];
    const unsigned char* row = uxt + (size_t)sp * ROWB;
    uint2 up = *(const uint2*)(row + 8 * j);            // 8 fp8 u values
    bf16x8 xx = *(const bf16x8*)(row + 128 + 16 * j);   // 8 bf16 xt values
    f32x2 u01 = fp8x2_to_f32(up.x & 0xffffu);
    f32x2 u23 = fp8x2_to_f32(up.x >> 16);
    f32x2 u45 = fp8x2_to_f32(up.y & 0xffffu);
    f32x2 u67 = fp8x2_to_f32(up.y >> 16);
    float uu[8] = {u01[0], u01[1], u23[0], u23[1], u45[0], u45[1], u67[0], u67[1]};
    float t = 0.f;
#pragma unroll
    for (int i = 0; i < 8; i++) {
      float h = uu[i] + vn[i];
      h = h > 0.f ? h : 0.f;
      t += h * w2v[i];
    }
    t += __shfl_xor(t, 1);
    t += __shfl_xor(t, 2);
    t += __shfl_xor(t, 4);
    t += __shfl_xor(t, 8);
    float gate = valid ? 1.0f / (1.0f + __expf(-(t + bias2))) : 0.f;
#pragma unroll
    for (int i = 0; i < 8; i++) acc[i] += gate * (float)xx[i];
  }
#pragma unroll
  for (int i = 0; i < 8; i++) acc[i] += __shfl_xor(acc[i], 16);
#pragma unroll
  for (int i = 0; i < 8; i++) acc[i] += __shfl_xor(acc[i], 32);
  if (g == 0) {
    float4 o0, o1;
    o0.x = acc[0]; o0.y = acc[1]; o0.z = acc[2]; o0.w = acc[3];
    o1.x = acc[4]; o1.y = acc[5]; o1.z = acc[6]; o1.w = acc[7];
    *(float4*)(out + n * F + 8 * j) = o0;
    *(float4*)(out + n * F + 8 * j + 4) = o1;
  }
}

extern "C" void kernel_launch(void* const* d_in, const int* in_sizes, int n_in,
                              void* d_out, int out_size, void* d_ws, size_t ws_size,
                              hipStream_t stream) {
  const float* x  = (const float*)d_in[0];
  const int* ei   = (const int*)d_in[1];   // int64 in reference -> int32 in harness
  const float* W  = (const float*)d_in[2];
  const float* b  = (const float*)d_in[3];
  const float* W1 = (const float*)d_in[4];
  const float* b1 = (const float*)d_in[5];
  const float* W2 = (const float*)d_in[6];
  const float* b2 = (const float*)d_in[7];
  float* out = (float*)d_out;

  char* ws = (char*)d_ws;
  unsigned char* uxt = (unsigned char*)ws;    // 19,200,000 B  [n]: u fp8 | xt bf16
  u16* vout    = (u16*)(ws + 19200000);       // 12,800,000 B
  u16* wt      = (u16*)(ws + 32000000);       //     32,768 B
  u16* w1t2    = (u16*)(ws + 32032768);       //     65,536 B
  int* offsets = (int*)(ws + 32098304);       //    200,004 B
  int* degp    = (int*)(ws + 32298308);       //    800,000 B  (4 partitions)
  int4* pb4    = (int4*)(ws + 33098308);      //    800,000 B
  int* obase   = (int*)(ws + 33898308);       //    800,000 B
  int* loc     = (int*)(ws + 34698308);       //  3,200,000 B
  u16* srcs16  = (u16*)(ws + 37898308);       //  1,600,000 B
  int* bsum    = (int*)(ws + 39498308);       //        196 B   total ~39.5 MB
  (void)ws_size;

  pre_kernel<<<ZERO_BLOCKS + PREP_BLOCKS, 256, 0, stream>>>(degp, W, W1, wt, w1t2);
  hist_kernel<<<HIST_BLOCKS, 256, 0, stream>>>(ei, degp, loc);
  scan1_kernel<<<SCAN_BLOCKS, 1024, 0, stream>>>(degp, offsets, pb4, bsum);
  scan23_kernel<<<(N_NODES + 255) / 256, 256, 0, stream>>>(offsets, bsum, pb4, obase);
  reorder_kernel<<<(N_EDGES + 255) / 256, 256, 0, stream>>>(ei, obase, loc, srcs16);
  node_gemm_kernel<<<(N_NODES + 63) / 64, 256, 0, stream>>>(x, wt, w1t2, b, b1, uxt, vout);
  edge_fused_kernel<<<(N_NODES * 64 + 255) / 256, 256, 0, stream>>>(
      uxt, vout, offsets, srcs16, W2, b2, out);
}